// Round 11
// baseline (9701.357 us; speedup 1.0000x reference)
//
#include <hip/hip_runtime.h>

// Problem constants
#define TSTEPS 300
// d_out float-element offsets: [outs 300*64*2 | r_m1 | r_pmd | r_s1]
#define OFF_RM1  38400
#define RSTRIDE  9830400    // 300*64*512 per rate region

// Geometry: 4 domains x 16 batch rows. Block = (dom, src-region, colblock).
// src block stages ONE rate panel (16x512) and computes BOTH matrices fed by
// that source: own-recurrent (keeps) + message (exports partial).
// XCD pinning heuristic: XCD = blk&7 = src*2 + (dom&1) -> 16 blocks/XCD
// sharing the same 2 MB weight pair => L2-resident.
// EXACT revert to the round-5 GREEN run (passed, 9602us, absmax 0.0039).
#define DOMS 4
#define DROWS 16
#define CPD 24              // compute blocks per domain (barrier population)
#define NBLK 128            // grid (28 blocks decode to no-role and exit)
#define THREADS 512
#define PAD 516             // LDS panel row pitch (floats): conflict-free

// ws float layout:
//   [0 .. 98303]  partials P[dom][edge][c][16][64]  (edge = exporting src)
//   [98304 .. ]   ints: flags[(dom*3+edge)*8+c] stride 16; barctr[dom] at 1536+dom*16
#define WS_INT_F 98304
#define WS_INTS  1600
#define WS_TOTAL 99904

typedef float f4 __attribute__((ext_vector_type(4)));
typedef unsigned long long u64;

// sc1 write-through publish (agent-visible, no fences) — rounds 2/4/5 proven
__device__ __forceinline__ void publish16(float* p, f4 v) {
  union { f4 f; u64 q[2]; } u; u.f = v;
  __hip_atomic_store((u64*)p,       u.q[0], __ATOMIC_RELAXED, __HIP_MEMORY_SCOPE_AGENT);
  __hip_atomic_store(((u64*)p) + 1, u.q[1], __ATOMIC_RELAXED, __HIP_MEMORY_SCOPE_AGENT);
}
// coherent read of reused buffers (bypasses stale local L2) — round-2 proven
__device__ __forceinline__ f4 fetch4(const float* p) {
  f4 v;
  v.x = __hip_atomic_load(p + 0, __ATOMIC_RELAXED, __HIP_MEMORY_SCOPE_AGENT);
  v.y = __hip_atomic_load(p + 1, __ATOMIC_RELAXED, __HIP_MEMORY_SCOPE_AGENT);
  v.z = __hip_atomic_load(p + 2, __ATOMIC_RELAXED, __HIP_MEMORY_SCOPE_AGENT);
  v.w = __hip_atomic_load(p + 3, __ATOMIC_RELAXED, __HIP_MEMORY_SCOPE_AGENT);
  return v;
}

// full-row out dot (one wave wide), global-pointer version for the writer
__device__ __forceinline__ void out_dot(const float* rrow, const float* W_out,
                                        float& o0, float& o1) {
  const int lane = threadIdx.x & 63;
  f4 ra = *(const f4*)(rrow + lane * 8);
  f4 rb = *(const f4*)(rrow + lane * 8 + 4);
  f4 w0 = *(const f4*)(W_out + lane * 16);
  f4 w1 = *(const f4*)(W_out + lane * 16 + 4);
  f4 w2 = *(const f4*)(W_out + lane * 16 + 8);
  f4 w3 = *(const f4*)(W_out + lane * 16 + 12);
  o0 = ra.x*w0.x + ra.y*w0.z + ra.z*w1.x + ra.w*w1.z
     + rb.x*w2.x + rb.y*w2.z + rb.z*w3.x + rb.w*w3.z;
  o1 = ra.x*w0.y + ra.y*w0.w + ra.z*w1.y + ra.w*w1.w
     + rb.x*w2.y + rb.y*w2.w + rb.z*w3.y + rb.w*w3.w;
  #pragma unroll
  for (int m = 1; m < 64; m <<= 1) {
    o0 += __shfl_xor(o0, m, 64);
    o1 += __shfl_xor(o1, m, 64);
  }
}

// ---------------------------------------------------------------------------
__global__ __launch_bounds__(256) void rnn_init(float* ws, float* dout) {
  int gid = blockIdx.x * blockDim.x + threadIdx.x;
  int stride = gridDim.x * blockDim.x;
  int* wi = (int*)(ws + WS_INT_F);
  for (int i = gid; i < WS_INTS; i += stride) wi[i] = 0;
  for (int i = gid; i < 128; i += stride) dout[i] = 0.f;
  for (int i = gid; i < 3 * 32768; i += stride) {
    int rr = i >> 15, j = i & 32767;
    dout[OFF_RM1 + (size_t)rr * RSTRIDE + j] = 0.f;
  }
}

// ---------------------------------------------------------------------------
__global__ __launch_bounds__(THREADS, 1) void rnn_persist(
    const float* __restrict__ stim,
    const float* __restrict__ W_rec_m1, const float* __restrict__ W_rec_pmd,
    const float* __restrict__ W_rec_s1,
    const float* __restrict__ W_pmd_m1, const float* __restrict__ b_pmd_m1,
    const float* __restrict__ W_m1_pmd, const float* __restrict__ b_m1_pmd,
    const float* __restrict__ W_s1_pmd, const float* __restrict__ b_s1_pmd,
    const float* __restrict__ W_in_s1,  const float* __restrict__ b_in_s1,
    const float* __restrict__ W_out_m1, const float* __restrict__ b_out_m1,
    const float* __restrict__ W_fb_pmd, const float* __restrict__ b_fb_pmd,
    float* __restrict__ ws, float* __restrict__ dout)
{
  __shared__ float panel[DROWS * PAD];   // one source-rate panel [16][PAD]
  __shared__ f4    scr[256];             // K-task-1 partials
  __shared__ float o_lds[32];            // outs[t-1] per row (o0,o1), src0 only

  const int blk = blockIdx.x;
  const int tid = threadIdx.x;
  const int x = blk & 7;                 // XCD slot (heuristic)
  const int jj = blk >> 3;

  int* ibase = (int*)(ws + WS_INT_F);

  // ================= passive lagging out-writer (XCD 6) =================
  if (x == 6) {
    if (jj >= DOMS) return;
    const int dom = jj;
    const int rowbase = dom * DROWS;
    int* ctr = ibase + 1536 + dom * 16;
    const float* rates0 = dout + OFF_RM1;
    const int wave = tid >> 6, lane = tid & 63;
    for (int t = 1; t < TSTEPS; ++t) {
      if (tid == 0) {
        while (__hip_atomic_load(ctr, __ATOMIC_RELAXED, __HIP_MEMORY_SCOPE_AGENT) < CPD * t)
          __builtin_amdgcn_s_sleep(2);
      }
      __syncthreads();
      #pragma unroll
      for (int h = 0; h < 2; ++h) {
        int rr = rowbase + wave + h * 8;
        float o0, o1;
        out_dot(rates0 + (size_t)t * 32768 + rr * 512, W_out_m1, o0, o1);
        if (lane == 0) {
          dout[(size_t)t * 128 + rr * 2]     = o0 + b_out_m1[0];
          dout[(size_t)t * 128 + rr * 2 + 1] = o1 + b_out_m1[1];
        }
      }
      __syncthreads();
    }
    return;
  }
  if (x == 7 || jj >= 16) return;

  // ================= compute blocks =================
  const int src = x >> 1;                  // source region 0=m1,1=pmd,2=s1
  const int dom = (x & 1) + 2 * (jj >> 3); // 0..3
  const int c   = jj & 7;                  // colblock (64 cols)
  const int rowbase = dom * DROWS;

  const int task = tid >> 8;               // 2 K-tasks x 256 threads
  const int s    = tid & 255;              // 16 rows x 16 col-quads
  const int bb   = s >> 4;
  const int nq   = s & 15;
  const int n    = c * 64 + nq * 4;        // global col 0..511
  const int row  = rowbase + bb;

  // matrices fed by this source: own (recurrent, kept) + export (message)
  const float *Wown, *Wexp;
  if (src == 0)      { Wown = W_rec_m1;  Wexp = W_m1_pmd; }
  else if (src == 1) { Wown = W_rec_pmd; Wexp = W_pmd_m1; }
  else               { Wown = W_rec_s1;  Wexp = W_s1_pmd; }

  // own-target bias (src == own target region)
  f4 bias, fbv0 = {0,0,0,0}, fbv1 = {0,0,0,0};
  if (src == 0) {
    bias = *(const f4*)(b_pmd_m1 + n);
    fbv0 = *(const f4*)(W_fb_pmd + n);        // feedback folded into export
    fbv1 = *(const f4*)(W_fb_pmd + 512 + n);
  } else if (src == 1) {
    bias  = *(const f4*)(b_m1_pmd + n);
    bias += *(const f4*)(b_s1_pmd + n);
    bias += *(const f4*)(b_fb_pmd + n);
  } else bias = *(const f4*)(b_in_s1 + n);

  // partial scratch + flags
  float* Pexp = ws + ((size_t)(dom * 3 + src) * 8 + c) * 1024;
  float* Prd0 = ws + ((size_t)(dom * 3 + ((src == 0) ? 1 : 0)) * 8 + c) * 1024;
  float* Prd2 = ws + ((size_t)(dom * 3 + 2) * 8 + c) * 1024;
  int* myflag = ibase + ((dom * 3 + src) * 8 + c) * 16;
  int* rdf0   = ibase + ((dom * 3 + ((src == 0) ? 1 : 0)) * 8 + c) * 16;
  int* rdf2   = ibase + ((dom * 3 + 2) * 8 + c) * 16;
  int* ctr    = ibase + 1536 + dom * 16;
  const int off = bb * 64 + nq * 4;

  f4 xv = {0.f, 0.f, 0.f, 0.f};            // x-state in registers (task0)

  for (int t = 1; t < TSTEPS; ++t) {
    // ---- burst-stage the source panel (16 rows x 512) ----
    {
      const float* srcp = dout + OFF_RM1 + (size_t)src * RSTRIDE
                        + (size_t)(t - 1) * 32768 + rowbase * 512;
      f4 tmp[4];
      #pragma unroll
      for (int i = 0; i < 4; ++i) {
        int j2 = tid + i * 512;
        tmp[i] = *(const f4*)(srcp + (j2 >> 7) * 512 + (j2 & 127) * 4);
      }
      #pragma unroll
      for (int i = 0; i < 4; ++i) {
        int j2 = tid + i * 512;
        *(f4*)(panel + (j2 >> 7) * PAD + (j2 & 127) * 4) = tmp[i];
      }
    }
    __syncthreads();

    // ---- src0: outs[t-1] from the staged rm1 panel (for feedback fold) ----
    if (src == 0 && t >= 2) {
      int rr = tid >> 5, kcl = tid & 31;
      const float* pr = panel + rr * PAD;
      float o0 = 0.f, o1 = 0.f;
      #pragma unroll
      for (int i = 0; i < 4; ++i) {
        int k = kcl * 4 + i * 128;
        f4 r  = *(const f4*)(pr + k);
        f4 wa = *(const f4*)(W_out_m1 + k * 2);
        f4 wb = *(const f4*)(W_out_m1 + k * 2 + 4);
        o0 += r.x*wa.x + r.y*wa.z + r.z*wb.x + r.w*wb.z;
        o1 += r.x*wa.y + r.y*wa.w + r.z*wb.y + r.w*wb.w;
      }
      #pragma unroll
      for (int m = 1; m < 32; m <<= 1) {
        o0 += __shfl_xor(o0, m, 64);
        o1 += __shfl_xor(o1, m, 64);
      }
      if ((tid & 31) == 0) {
        o_lds[rr * 2]     = o0 + b_out_m1[0];
        o_lds[rr * 2 + 1] = o1 + b_out_m1[1];
      }
    }

    // ---- dot 1: export (message) matrix ----
    f4 acc;
    {
      const float* wg  = Wexp + (size_t)(task * 256) * 512 + n;
      const float* pan = panel + bb * PAD + task * 256;
      f4 a = {0.f, 0.f, 0.f, 0.f};
      #pragma unroll 2
      for (int kk = 0; kk < 256; kk += 4) {
        f4 r  = *(const f4*)(pan + kk);
        f4 g0 = *(const f4*)(wg);
        f4 g1 = *(const f4*)(wg + 512);
        f4 g2 = *(const f4*)(wg + 1024);
        f4 g3 = *(const f4*)(wg + 1536);
        wg += 2048;
        a += r.x * g0; a += r.y * g1; a += r.z * g2; a += r.w * g3;
      }
      acc = a;
    }
    if (task == 1) scr[s] = acc;
    __syncthreads();
    if (task == 0) {
      f4 pe = acc + scr[s];
      if (src == 0 && t >= 2) {
        pe += o_lds[bb * 2]     * fbv0;
        pe += o_lds[bb * 2 + 1] * fbv1;
      }
      publish16(Pexp + off, pe);
    }
    __syncthreads();   // drains publishes (vmcnt 0) before flag release
    if (tid == 0)
      __hip_atomic_fetch_add(myflag, 1, __ATOMIC_RELAXED, __HIP_MEMORY_SCOPE_AGENT);

    // ---- dot 2: own recurrent matrix ----
    {
      const float* wg  = Wown + (size_t)(task * 256) * 512 + n;
      const float* pan = panel + bb * PAD + task * 256;
      f4 a = {0.f, 0.f, 0.f, 0.f};
      #pragma unroll 2
      for (int kk = 0; kk < 256; kk += 4) {
        f4 r  = *(const f4*)(pan + kk);
        f4 g0 = *(const f4*)(wg);
        f4 g1 = *(const f4*)(wg + 512);
        f4 g2 = *(const f4*)(wg + 1024);
        f4 g3 = *(const f4*)(wg + 1536);
        wg += 2048;
        a += r.x * g0; a += r.y * g1; a += r.z * g2; a += r.w * g3;
      }
      acc = a;
    }
    if (task == 1) scr[s] = acc;
    if (tid == 0) {       // poll needed import flags while others sync
      if (src == 0) {
        while (__hip_atomic_load(rdf0, __ATOMIC_RELAXED, __HIP_MEMORY_SCOPE_AGENT) < t)
          __builtin_amdgcn_s_sleep(1);
      } else if (src == 1) {
        while (__hip_atomic_load(rdf0, __ATOMIC_RELAXED, __HIP_MEMORY_SCOPE_AGENT) < t)
          __builtin_amdgcn_s_sleep(1);
        while (__hip_atomic_load(rdf2, __ATOMIC_RELAXED, __HIP_MEMORY_SCOPE_AGENT) < t)
          __builtin_amdgcn_s_sleep(1);
      }
    }
    __syncthreads();

    // ---- combine + leaky update + tanh + publish rates (task 0) ----
    if (task == 0) {
      f4 pre = acc + scr[s] + bias;
      if (src == 0) {
        pre += fetch4(Prd0 + off);                 // pmd_m1 import
      } else if (src == 1) {
        pre += fetch4(Prd0 + off);                 // m1_pmd (+folded feedback)
        pre += fetch4(Prd2 + off);                 // s1_pmd
      } else {
        const float* u = stim + (size_t)t * 640 + row * 10;
        #pragma unroll
        for (int j = 0; j < 10; ++j)
          pre += u[j] * *(const f4*)(W_in_s1 + j * 512 + n);
      }
      xv = 0.8f * xv + 0.2f * pre;
      f4 rv = {tanhf(xv.x), tanhf(xv.y), tanhf(xv.z), tanhf(xv.w)};
      publish16(dout + OFF_RM1 + (size_t)src * RSTRIDE + (size_t)t * 32768
                + row * 512 + n, rv);
    }

    // ---- domain barrier (24 compute blocks; monotonic counter) ----
    __syncthreads();   // drains rate publishes before arrival
    if (tid == 0) {
      __hip_atomic_fetch_add(ctr, 1, __ATOMIC_RELAXED, __HIP_MEMORY_SCOPE_AGENT);
      if (t < TSTEPS - 1) {
        while (__hip_atomic_load(ctr, __ATOMIC_RELAXED, __HIP_MEMORY_SCOPE_AGENT) < CPD * t)
          __builtin_amdgcn_s_sleep(1);
      }
    }
    __syncthreads();
  }
}

extern "C" void kernel_launch(void* const* d_in, const int* in_sizes, int n_in,
                              void* d_out, int out_size, void* d_ws, size_t ws_size,
                              hipStream_t stream) {
  const float* stim      = (const float*)d_in[0];
  const float* W_rec_m1  = (const float*)d_in[1];
  const float* W_rec_pmd = (const float*)d_in[2];
  const float* W_rec_s1  = (const float*)d_in[3];
  const float* W_pmd_m1  = (const float*)d_in[4];
  const float* b_pmd_m1  = (const float*)d_in[5];
  const float* W_m1_pmd  = (const float*)d_in[6];
  const float* b_m1_pmd  = (const float*)d_in[7];
  const float* W_s1_pmd  = (const float*)d_in[8];
  const float* b_s1_pmd  = (const float*)d_in[9];
  const float* W_in_s1   = (const float*)d_in[10];
  const float* b_in_s1   = (const float*)d_in[11];
  const float* W_out_m1  = (const float*)d_in[12];
  const float* b_out_m1  = (const float*)d_in[13];
  const float* W_fb_pmd  = (const float*)d_in[14];
  const float* b_fb_pmd  = (const float*)d_in[15];

  float* ws   = (float*)d_ws;
  float* dout = (float*)d_out;

  hipLaunchKernelGGL(rnn_init, dim3(256), dim3(256), 0, stream, ws, dout);

  void* args[] = {
    (void*)&stim,
    (void*)&W_rec_m1, (void*)&W_rec_pmd, (void*)&W_rec_s1,
    (void*)&W_pmd_m1, (void*)&b_pmd_m1,
    (void*)&W_m1_pmd, (void*)&b_m1_pmd,
    (void*)&W_s1_pmd, (void*)&b_s1_pmd,
    (void*)&W_in_s1,  (void*)&b_in_s1,
    (void*)&W_out_m1, (void*)&b_out_m1,
    (void*)&W_fb_pmd, (void*)&b_fb_pmd,
    (void*)&ws, (void*)&dout
  };
  hipLaunchCooperativeKernel((const void*)rnn_persist, dim3(NBLK), dim3(THREADS),
                             args, 0, stream);
}